// Round 14
// baseline (244.262 us; speedup 1.0000x reference)
//
#include <hip/hip_runtime.h>
#include <math.h>

#define BB 8192
#define DD 4096
#define EE 64

constexpr float NOISE_EPS = 0.01f;
constexpr int BM = 64;              // rows per block (main GEMM)
constexpr int NRB = BB / BM;        // row-blocks (128)

typedef __attribute__((ext_vector_type(8))) _Float16 f16x8;
typedef __attribute__((ext_vector_type(4))) float    f32x4;

__device__ __forceinline__ void split8(const float4& a, const float4& b,
                                       f16x8& hi, f16x8& mi) {
    float v[8] = {a.x, a.y, a.z, a.w, b.x, b.y, b.z, b.w};
    #pragma unroll
    for (int j = 0; j < 8; ++j) {
        _Float16 h = (_Float16)v[j];          // RN
        hi[j] = h;
        mi[j] = (_Float16)(v[j] - (float)h);
    }
}

// ---- pre-pass: pack weights into fp16 hi/mid planes in FRAGMENT order ----
// Also zeroes the split-K arrival counters (graph-replay safe).
__global__ __launch_bounds__(256) void wsplit_pack(
    const float* __restrict__ gw, const float* __restrict__ ngw,
    char* __restrict__ wpk, int* __restrict__ counters)
{
    if (blockIdx.x == 0 && threadIdx.x < NRB) counters[threadIdx.x] = 0;

    const int gid = blockIdx.x * 256 + threadIdx.x;   // 65536 threads
    const int r   = gid >> 9;                         // 0..127
    const int kc  = gid & 511;                        // 8-float chunk in row
    const int k0  = kc * 8;
    const float* src = (r < EE) ? gw + (size_t)r * DD + k0
                                : ngw + (size_t)(r - EE) * DD + k0;
    float4 a = *reinterpret_cast<const float4*>(src);
    float4 b = *reinterpret_cast<const float4*>(src + 4);
    f16x8 hi, mi;
    split8(a, b, hi, mi);
    const int T    = k0 >> 5;
    const int kq   = (k0 >> 3) & 3;
    const int cb   = r >> 4;
    const int lane = kq * 16 + (r & 15);
    char* base = wpk + (size_t)T * 16384;
    *reinterpret_cast<f16x8*>(base + ((cb * 2 + 0) * 64 + lane) * 16) = hi;
    *reinterpret_cast<f16x8*>(base + ((cb * 2 + 1) * 64 + lane) * 16) = mi;
}

// --------------------------- fused GEMM + epilogue -------------------------
// Main loop identical to round 12 (best known: producer/consumer waves,
// B read-once from frag-packed global, split-once x staging). After the
// partial write, blocks arrive at a per-row-block counter; the LAST block
// sums the SK slices and runs the top-2/softmax epilogue inline.
template <int SK>
__global__ __launch_bounds__(512, 4) void gating_fused(
    const float* __restrict__ x,
    const char*  __restrict__ wpk,
    float* __restrict__ partial,       // [SK][BB][128]
    int*   __restrict__ counters,      // [NRB]
    const float* __restrict__ noise,   // [B, E]
    float* __restrict__ out)           // gates [B,E] then load [B,E]
{
    constexpr int KC   = DD / SK;
    constexpr int NKS  = KC / 64;       // K-steps, even
    constexpr int GMAX = 2 * NKS - 1;   // last 32-k chunk index in this part

    __shared__ __align__(1024) char xls[2][16384];
    __shared__ int s_last;

    const int tid  = threadIdx.x;
    const int bid  = blockIdx.x;
    const int sk   = bid & (SK - 1);
    const int rbid = bid / SK;
    const int row0 = rbid * BM;
    const int lane = tid & 63;
    const int wv   = tid >> 6;
    const bool producer = (wv < 4);
    const int l15  = lane & 15;
    const int kq   = lane >> 4;

    char* buf0 = (char*)xls[0];
    char* buf1 = (char*)xls[1];

    // =================== producer setup (waves 0..3) ===================
    const int pr = tid >> 2;            // 0..63 (valid for tid<256)
    const int ps = tid & 3;             // 16-float slot
    const float* xg = x + (size_t)(row0 + pr) * DD + sk * KC + ps * 16;
    const int swp   = pr & 7;
    const int wb    = pr * 256;
    const int wo_h0 = wb       + (((2 * ps)     ^ swp) << 4);
    const int wo_m0 = wb + 128 + (((2 * ps)     ^ swp) << 4);
    const int wo_h1 = wb       + (((2 * ps + 1) ^ swp) << 4);
    const int wo_m1 = wb + 128 + (((2 * ps + 1) ^ swp) << 4);

    #define LOADX(t, V0, V1, V2, V3) do {                                      \
        const float* _s = xg + (size_t)(t) * 64;                               \
        V0 = *reinterpret_cast<const float4*>(_s);                             \
        V1 = *reinterpret_cast<const float4*>(_s + 4);                         \
        V2 = *reinterpret_cast<const float4*>(_s + 8);                         \
        V3 = *reinterpret_cast<const float4*>(_s + 12);                        \
    } while (0)

    #define WSPLIT(bp, V0, V1, V2, V3) do {                                    \
        f16x8 _h, _m;                                                          \
        split8(V0, V1, _h, _m);                                                \
        *reinterpret_cast<f16x8*>((bp) + wo_h0) = _h;                          \
        *reinterpret_cast<f16x8*>((bp) + wo_m0) = _m;                          \
        split8(V2, V3, _h, _m);                                                \
        *reinterpret_cast<f16x8*>((bp) + wo_h1) = _h;                          \
        *reinterpret_cast<f16x8*>((bp) + wo_m1) = _m;                          \
    } while (0)

    // =================== consumer setup (waves 4..7) ===================
    const int cw = wv - 4;              // 0..3 ; owns cbs 2cw, 2cw+1
    int rbase[4], swz[4];
    #pragma unroll
    for (int ms = 0; ms < 4; ++ms) {
        const int r = ms * 16 + l15;
        rbase[ms] = r * 256;
        swz[ms]   = r & 7;
    }
    const char* wpkB = wpk + ((size_t)(sk * NKS * 2) << 14)
                           + ((cw & 3) * 4096) + lane * 16;

    f32x4 acc[4][2];
    #pragma unroll
    for (int ms = 0; ms < 4; ++ms) {
        acc[ms][0] = {0.f, 0.f, 0.f, 0.f};
        acc[ms][1] = {0.f, 0.f, 0.f, 0.f};
    }

    #define LOADB(g, H0, M0, H1, M1) do {                                      \
        const char* _b = wpkB + ((size_t)(g) << 14);                           \
        H0 = *reinterpret_cast<const f16x8*>(_b);                              \
        M0 = *reinterpret_cast<const f16x8*>(_b + 1024);                       \
        H1 = *reinterpret_cast<const f16x8*>(_b + 2048);                       \
        M1 = *reinterpret_cast<const f16x8*>(_b + 3072);                       \
    } while (0)

    #define CHUNK(bufp, gc, H0, M0, H1, M1) do {                               \
        const char* _xb = (bufp);                                              \
        const int _c = (gc) & 1;                                               \
        f16x8 ah[4], am[4];                                                    \
        _Pragma("unroll")                                                      \
        for (int ms = 0; ms < 4; ++ms) {                                       \
            const int so = (((_c << 2) | kq) ^ swz[ms]) << 4;                  \
            ah[ms] = *reinterpret_cast<const f16x8*>(_xb + rbase[ms] + so);    \
            am[ms] = *reinterpret_cast<const f16x8*>(_xb + rbase[ms] + 128 + so);\
        }                                                                      \
        _Pragma("unroll")                                                      \
        for (int ms = 0; ms < 4; ++ms) {                                       \
            acc[ms][0] = __builtin_amdgcn_mfma_f32_16x16x32_f16(ah[ms], H0, acc[ms][0], 0,0,0); \
            acc[ms][1] = __builtin_amdgcn_mfma_f32_16x16x32_f16(ah[ms], H1, acc[ms][1], 0,0,0); \
        }                                                                      \
        _Pragma("unroll")                                                      \
        for (int ms = 0; ms < 4; ++ms) {                                       \
            acc[ms][0] = __builtin_amdgcn_mfma_f32_16x16x32_f16(am[ms], H0, acc[ms][0], 0,0,0); \
            acc[ms][1] = __builtin_amdgcn_mfma_f32_16x16x32_f16(am[ms], H1, acc[ms][1], 0,0,0); \
        }                                                                      \
        _Pragma("unroll")                                                      \
        for (int ms = 0; ms < 4; ++ms) {                                       \
            acc[ms][0] = __builtin_amdgcn_mfma_f32_16x16x32_f16(ah[ms], M0, acc[ms][0], 0,0,0); \
            acc[ms][1] = __builtin_amdgcn_mfma_f32_16x16x32_f16(ah[ms], M1, acc[ms][1], 0,0,0); \
        }                                                                      \
        { const int _g = (gc) + 2;                                             \
          LOADB((_g <= GMAX) ? _g : GMAX, H0, M0, H1, M1); }                   \
    } while (0)

    float4 xa0, xa1, xa2, xa3;
    float4 xb0, xb1, xb2, xb3;
    f16x8 pH0, pM0, pH1, pM1;
    f16x8 qH0, qM0, qH1, qM1;

    // ---- prologue ----
    if (producer) {
        LOADX(0, xa0, xa1, xa2, xa3);
        WSPLIT(buf0, xa0, xa1, xa2, xa3);
        LOADX(1, xb0, xb1, xb2, xb3);
    } else {
        LOADB(0, pH0, pM0, pH1, pM1);
        LOADB(1, qH0, qM0, qH1, qM1);
    }

    // ---- main loop (2 steps per trip; 1 lgkmcnt+barrier per step) ----
    for (int t = 0; t < NKS; t += 2) {
        asm volatile("s_waitcnt lgkmcnt(0)" ::: "memory");
        __builtin_amdgcn_s_barrier();
        if (producer) {
            if (t + 2 < NKS) LOADX(t + 2, xa0, xa1, xa2, xa3);
            WSPLIT(buf1, xb0, xb1, xb2, xb3);
        } else {
            CHUNK(buf0, 2 * t,     pH0, pM0, pH1, pM1);
            CHUNK(buf0, 2 * t + 1, qH0, qM0, qH1, qM1);
        }

        asm volatile("s_waitcnt lgkmcnt(0)" ::: "memory");
        __builtin_amdgcn_s_barrier();
        if (producer) {
            if (t + 3 < NKS) LOADX(t + 3, xb0, xb1, xb2, xb3);
            if (t + 2 < NKS) WSPLIT(buf0, xa0, xa1, xa2, xa3);
        } else {
            CHUNK(buf1, 2 * t + 2, pH0, pM0, pH1, pM1);
            CHUNK(buf1, 2 * t + 3, qH0, qM0, qH1, qM1);
        }
    }

    #undef LOADX
    #undef WSPLIT
    #undef LOADB
    #undef CHUNK

    // ---- partial slice out (consumers only; deterministic) ----
    if (!producer) {
        const size_t pbase = ((size_t)sk * BB + row0) * 128;
        #pragma unroll
        for (int ms = 0; ms < 4; ++ms) {
            #pragma unroll
            for (int cb = 0; cb < 2; ++cb) {
                #pragma unroll
                for (int j = 0; j < 4; ++j) {
                    const int r = ms * 16 + kq * 4 + j;
                    const int c = (2 * cw + cb) * 16 + l15;
                    partial[pbase + (size_t)r * 128 + c] = acc[ms][cb][j];
                }
            }
        }
    }

    // ---- split-K arrival: last block for this row-block runs epilogue ----
    __threadfence();                       // release partial stores (device)
    __syncthreads();                       // all threads' stores fenced
    if (tid == 0) s_last = (atomicAdd(&counters[rbid], 1) == SK - 1);
    __syncthreads();
    if (!s_last) return;
    __threadfence();                       // acquire other blocks' partials

    // epilogue: 2 passes x 32 rows; 16 lanes per row, 4 experts per lane
    #pragma unroll
    for (int pass = 0; pass < 2; ++pass) {
        const int r    = pass * 32 + wv * 4 + kq;   // 0..63
        const int grow = row0 + r;
        const int s    = l15;

        const float* pb = partial + (size_t)grow * 128 + 4 * s;
        float4 c4 = {0.f,0.f,0.f,0.f}, n4 = {0.f,0.f,0.f,0.f};
        #pragma unroll
        for (int k = 0; k < SK; ++k) {
            const float* p = pb + (size_t)k * BB * 128;
            float4 a = *reinterpret_cast<const float4*>(p);
            float4 b = *reinterpret_cast<const float4*>(p + 64);
            c4.x += a.x; c4.y += a.y; c4.z += a.z; c4.w += a.w;
            n4.x += b.x; n4.y += b.y; n4.z += b.z; n4.w += b.w;
        }

        float4 nz = *reinterpret_cast<const float4*>(noise + (size_t)grow * EE + 4 * s);

        float cc[4] = {c4.x, c4.y, c4.z, c4.w};
        float nl[4] = {n4.x, n4.y, n4.z, n4.w};
        float m1 = -3.4e38f, m2 = -3.4e38f;
        int   i1 = -1, i2 = -1;
        float cmax = -3.4e38f;
        #pragma unroll
        for (int j = 0; j < 4; ++j) {
            const int e = 4 * s + j;
            float sp  = fmaxf(nl[j], 0.0f) + log1pf(expf(-fabsf(nl[j])));
            float nzj = (j == 0) ? nz.x : (j == 1) ? nz.y : (j == 2) ? nz.z : nz.w;
            float vno = fmaf(nzj * sp, NOISE_EPS, cc[j]);
            if (vno > m1)      { m2 = m1; i2 = i1; m1 = vno; i1 = e; }
            else if (vno > m2) { m2 = vno; i2 = e; }
            cmax = fmaxf(cmax, cc[j]);
        }

        #pragma unroll
        for (int m = 1; m < 16; m <<= 1) {
            float b1 = __shfl_xor(m1, m, 16);
            int  bi1 = __shfl_xor(i1, m, 16);
            float b2 = __shfl_xor(m2, m, 16);
            int  bi2 = __shfl_xor(i2, m, 16);
            cmax = fmaxf(cmax, __shfl_xor(cmax, m, 16));

            bool bwin = (b1 > m1) || (b1 == m1 && bi1 < i1);
            float t1; int ti1; float t2; int ti2;
            if (bwin) {
                t1 = b1; ti1 = bi1;
                bool aw = (m1 > b2) || (m1 == b2 && i1 < bi2);
                t2 = aw ? m1 : b2; ti2 = aw ? i1 : bi2;
            } else {
                t1 = m1; ti1 = i1;
                bool bw = (b1 > m2) || (b1 == m2 && bi1 < i2);
                t2 = bw ? b1 : m2; ti2 = bw ? bi1 : i2;
            }
            m1 = t1; i1 = ti1; m2 = t2; i2 = ti2;
        }

        float tq = expf(m2 - m1);
        float p1 = 1.0f / (1.0f + tq);
        float p2 = tq * p1;

        float e0 = expf(cc[0] - cmax);
        float e1 = expf(cc[1] - cmax);
        float e2 = expf(cc[2] - cmax);
        float e3 = expf(cc[3] - cmax);
        float sum = e0 + e1 + e2 + e3;
        #pragma unroll
        for (int m = 1; m < 16; m <<= 1) sum += __shfl_xor(sum, m, 16);
        float inv = 1.0f / sum;

        const int eb = 4 * s;
        float4 gt;
        gt.x = (eb     == i1) ? p1 : (eb     == i2) ? p2 : 0.0f;
        gt.y = (eb + 1 == i1) ? p1 : (eb + 1 == i2) ? p2 : 0.0f;
        gt.z = (eb + 2 == i1) ? p1 : (eb + 2 == i2) ? p2 : 0.0f;
        gt.w = (eb + 3 == i1) ? p1 : (eb + 3 == i2) ? p2 : 0.0f;
        float4 ld = {e0 * inv, e1 * inv, e2 * inv, e3 * inv};

        *reinterpret_cast<float4*>(out + (size_t)grow * EE + eb) = gt;
        *reinterpret_cast<float4*>(out + (size_t)BB * EE + (size_t)grow * EE + eb) = ld;
    }
}

extern "C" void kernel_launch(void* const* d_in, const int* in_sizes, int n_in,
                              void* d_out, int out_size, void* d_ws, size_t ws_size,
                              hipStream_t stream) {
    const float* x     = (const float*)d_in[0];
    const float* gw    = (const float*)d_in[1];
    const float* ngw   = (const float*)d_in[2];
    const float* noise = (const float*)d_in[3];
    float* out = (float*)d_out;

    const size_t MB = 1024 * 1024;
    char*  wpk      = (char*)d_ws;                               // 2 MB packed w
    float* partial  = (float*)(wpk + 2 * MB);                    // SK * 4 MB
    // counters live after the largest partial region we might use (SK=4: 16MB)
    int*   counters = (int*)(wpk + 2 * MB + 16 * MB);            // NRB ints

    hipLaunchKernelGGL(wsplit_pack, dim3(256), dim3(256), 0, stream,
                       gw, ngw, wpk, counters);

    if (ws_size >= 19 * MB) {
        hipLaunchKernelGGL(gating_fused<4>, dim3(NRB * 4), dim3(512), 0, stream,
                           x, wpk, partial, counters, noise, out);
    } else if (ws_size >= 11 * MB) {
        counters = (int*)(wpk + 2 * MB + 8 * MB);
        hipLaunchKernelGGL(gating_fused<2>, dim3(NRB * 2), dim3(512), 0, stream,
                           x, wpk, partial, counters, noise, out);
    } else {
        counters = (int*)(wpk + 2 * MB + 4 * MB);
        hipLaunchKernelGGL(gating_fused<1>, dim3(NRB), dim3(512), 0, stream,
                           x, wpk, partial, counters, noise, out);
    }
}

// Round 16
// 49.124 us; speedup vs baseline: 4.9724x; 4.9724x over previous
//
#include <hip/hip_runtime.h>
#include <math.h>

#define BB 8192
#define DD 4096
#define EE 64

constexpr float NOISE_EPS = 0.01f;
constexpr int BM = 64;              // rows per block (main GEMM)

typedef __attribute__((ext_vector_type(8))) _Float16 f16x8;
typedef __attribute__((ext_vector_type(4))) float    f32x4;

__device__ __forceinline__ void split8(const float4& a, const float4& b,
                                       f16x8& hi, f16x8& mi) {
    float v[8] = {a.x, a.y, a.z, a.w, b.x, b.y, b.z, b.w};
    #pragma unroll
    for (int j = 0; j < 8; ++j) {
        _Float16 h = (_Float16)v[j];          // RN
        hi[j] = h;
        mi[j] = (_Float16)(v[j] - (float)h);
    }
}

// Barrier that the compiler cannot reorder memory ops around: pre-fence on own
// LDS ops, s_barrier, then a hard scheduling fence (s_barrier is NOT an IR-level
// memory fence; without sched_barrier(0) consumer ds_reads can hoist above it).
__device__ __forceinline__ void block_barrier() {
    asm volatile("s_waitcnt lgkmcnt(0)" ::: "memory");
    __builtin_amdgcn_s_barrier();
    __builtin_amdgcn_sched_barrier(0);
    asm volatile("" ::: "memory");
}

// ---- pre-pass: pack weights into fp16 hi/mid planes in FRAGMENT order ----
// wpk chunk T (16 KB, T = global 32-k chunk): [cb 0..7][plane 0..1][lane 0..63] x 16B
// content(cb,p,lane): 8 fp16, weight row cb*16+(lane&15), k = T*32+(lane>>4)*8..
__global__ __launch_bounds__(256) void wsplit_pack(
    const float* __restrict__ gw, const float* __restrict__ ngw,
    char* __restrict__ wpk)
{
    const int gid = blockIdx.x * 256 + threadIdx.x;   // 65536 threads
    const int r   = gid >> 9;                         // 0..127
    const int kc  = gid & 511;                        // 8-float chunk in row
    const int k0  = kc * 8;
    const float* src = (r < EE) ? gw + (size_t)r * DD + k0
                                : ngw + (size_t)(r - EE) * DD + k0;
    float4 a = *reinterpret_cast<const float4*>(src);
    float4 b = *reinterpret_cast<const float4*>(src + 4);
    f16x8 hi, mi;
    split8(a, b, hi, mi);
    const int T    = k0 >> 5;
    const int kq   = (k0 >> 3) & 3;
    const int cb   = r >> 4;
    const int lane = kq * 16 + (r & 15);
    char* base = wpk + (size_t)T * 16384;
    *reinterpret_cast<f16x8*>(base + ((cb * 2 + 0) * 64 + lane) * 16) = hi;
    *reinterpret_cast<f16x8*>(base + ((cb * 2 + 1) * 64 + lane) * 16) = mi;
}

// ------------------------------- main GEMM --------------------------------
// Producer/consumer wave split: waves 0..3 stage x (global->reg->split->LDS);
// waves 4..7 each own 2 column-blocks (32 cols) and run ds_read+MFMA with
// B fragments straight from the frag-packed global buffer (read-once/block).
// K-step = 64, double-buffered; 1 hardened barrier per step; all global loads
// compiler-counted (stay in flight across barriers).
template <int SK>
__global__ __launch_bounds__(512, 4) void gating_main(
    const float* __restrict__ x,
    const char*  __restrict__ wpk,
    float* __restrict__ partial)       // [SK][BB][128]
{
    constexpr int KC   = DD / SK;
    constexpr int NKS  = KC / 64;       // K-steps (16 for SK=4), even
    constexpr int GMAX = 2 * NKS - 1;   // last 32-k chunk index in this part

    // [buf][row 0..63][plane 0..1][8 swizzled 16B k-slots] = 2 x 16 KB
    __shared__ __align__(1024) char xls[2][16384];

    const int tid  = threadIdx.x;
    const int bid  = blockIdx.x;
    const int sk   = bid & (SK - 1);
    const int row0 = (bid / SK) * BM;
    const int lane = tid & 63;
    const int wv   = tid >> 6;
    const bool producer = (wv < 4);
    const int l15  = lane & 15;
    const int kq   = lane >> 4;

    char* buf0 = (char*)xls[0];
    char* buf1 = (char*)xls[1];

    // =================== producer setup (waves 0..3) ===================
    const int pr = tid >> 2;            // 0..63 (valid for tid<256)
    const int ps = tid & 3;             // 16-float slot
    const float* xg = x + (size_t)(row0 + pr) * DD + sk * KC + ps * 16;
    const int swp   = pr & 7;
    const int wb    = pr * 256;
    const int wo_h0 = wb       + (((2 * ps)     ^ swp) << 4);
    const int wo_m0 = wb + 128 + (((2 * ps)     ^ swp) << 4);
    const int wo_h1 = wb       + (((2 * ps + 1) ^ swp) << 4);
    const int wo_m1 = wb + 128 + (((2 * ps + 1) ^ swp) << 4);

    #define LOADX(t, V0, V1, V2, V3) do {                                      \
        const float* _s = xg + (size_t)(t) * 64;                               \
        V0 = *reinterpret_cast<const float4*>(_s);                             \
        V1 = *reinterpret_cast<const float4*>(_s + 4);                         \
        V2 = *reinterpret_cast<const float4*>(_s + 8);                         \
        V3 = *reinterpret_cast<const float4*>(_s + 12);                        \
    } while (0)

    #define WSPLIT(bp, V0, V1, V2, V3) do {                                    \
        f16x8 _h, _m;                                                          \
        split8(V0, V1, _h, _m);                                                \
        *reinterpret_cast<f16x8*>((bp) + wo_h0) = _h;                          \
        *reinterpret_cast<f16x8*>((bp) + wo_m0) = _m;                          \
        split8(V2, V3, _h, _m);                                                \
        *reinterpret_cast<f16x8*>((bp) + wo_h1) = _h;                          \
        *reinterpret_cast<f16x8*>((bp) + wo_m1) = _m;                          \
    } while (0)

    // =================== consumer setup (waves 4..7) ===================
    const int cw = wv - 4;              // 0..3 ; owns cbs 2cw, 2cw+1
    int rbase[4], swz[4];
    #pragma unroll
    for (int ms = 0; ms < 4; ++ms) {
        const int r = ms * 16 + l15;
        rbase[ms] = r * 256;
        swz[ms]   = r & 7;
    }
    // consumer's 4 KB contiguous B slice: [cb0 hi][cb0 mi][cb1 hi][cb1 mi]
    const char* wpkB = wpk + ((size_t)(sk * NKS * 2) << 14)
                           + ((cw & 3) * 4096) + lane * 16;

    f32x4 acc[4][2];
    #pragma unroll
    for (int ms = 0; ms < 4; ++ms) {
        acc[ms][0] = {0.f, 0.f, 0.f, 0.f};
        acc[ms][1] = {0.f, 0.f, 0.f, 0.f};
    }

    #define LOADB(g, H0, M0, H1, M1) do {                                      \
        const char* _b = wpkB + ((size_t)(g) << 14);                           \
        H0 = *reinterpret_cast<const f16x8*>(_b);                              \
        M0 = *reinterpret_cast<const f16x8*>(_b + 1024);                       \
        H1 = *reinterpret_cast<const f16x8*>(_b + 2048);                       \
        M1 = *reinterpret_cast<const f16x8*>(_b + 3072);                       \
    } while (0)

    // one 32-k chunk: 8 ds_read_b128 + 24 MFMA + JIT B reload (2 ahead)
    #define CHUNK(bufp, gc, H0, M0, H1, M1) do {                               \
        const char* _xb = (bufp);                                              \
        const int _c = (gc) & 1;                                               \
        f16x8 ah[4], am[4];                                                    \
        _Pragma("unroll")                                                      \
        for (int ms = 0; ms < 4; ++ms) {                                       \
            const int so = (((_c << 2) | kq) ^ swz[ms]) << 4;                  \
            ah[ms] = *reinterpret_cast<const f16x8*>(_xb + rbase[ms] + so);    \
            am[ms] = *reinterpret_cast<const f16x8*>(_xb + rbase[ms] + 128 + so);\
        }                                                                      \
        _Pragma("unroll")                                                      \
        for (int ms = 0; ms < 4; ++ms) {                                       \
            acc[ms][0] = __builtin_amdgcn_mfma_f32_16x16x32_f16(ah[ms], H0, acc[ms][0], 0,0,0); \
            acc[ms][1] = __builtin_amdgcn_mfma_f32_16x16x32_f16(ah[ms], H1, acc[ms][1], 0,0,0); \
        }                                                                      \
        _Pragma("unroll")                                                      \
        for (int ms = 0; ms < 4; ++ms) {                                       \
            acc[ms][0] = __builtin_amdgcn_mfma_f32_16x16x32_f16(am[ms], H0, acc[ms][0], 0,0,0); \
            acc[ms][1] = __builtin_amdgcn_mfma_f32_16x16x32_f16(am[ms], H1, acc[ms][1], 0,0,0); \
        }                                                                      \
        _Pragma("unroll")                                                      \
        for (int ms = 0; ms < 4; ++ms) {                                       \
            acc[ms][0] = __builtin_amdgcn_mfma_f32_16x16x32_f16(ah[ms], M0, acc[ms][0], 0,0,0); \
            acc[ms][1] = __builtin_amdgcn_mfma_f32_16x16x32_f16(ah[ms], M1, acc[ms][1], 0,0,0); \
        }                                                                      \
        { const int _g = (gc) + 2;                                             \
          LOADB((_g <= GMAX) ? _g : GMAX, H0, M0, H1, M1); }                   \
    } while (0)

    float4 xa0, xa1, xa2, xa3;          // x reg set A
    float4 xb0, xb1, xb2, xb3;          // x reg set B
    f16x8 pH0, pM0, pH1, pM1;           // B set for even chunks
    f16x8 qH0, qM0, qH1, qM1;           // B set for odd chunks

    // ---- prologue ----
    if (producer) {
        LOADX(0, xa0, xa1, xa2, xa3);
        WSPLIT(buf0, xa0, xa1, xa2, xa3);
        LOADX(1, xb0, xb1, xb2, xb3);
    } else {
        LOADB(0, pH0, pM0, pH1, pM1);
        LOADB(1, qH0, qM0, qH1, qM1);
    }

    // ---- main loop (2 steps per trip; 1 hardened barrier per step) ----
    for (int t = 0; t < NKS; t += 2) {
        // even step t: consumers compute buf0; producers write x(t+1)->buf1
        block_barrier();
        if (producer) {
            if (t + 2 < NKS) LOADX(t + 2, xa0, xa1, xa2, xa3);
            WSPLIT(buf1, xb0, xb1, xb2, xb3);
        } else {
            CHUNK(buf0, 2 * t,     pH0, pM0, pH1, pM1);
            CHUNK(buf0, 2 * t + 1, qH0, qM0, qH1, qM1);
        }

        // odd step t+1: consumers compute buf1; producers write x(t+2)->buf0
        block_barrier();
        if (producer) {
            if (t + 3 < NKS) LOADX(t + 3, xb0, xb1, xb2, xb3);
            if (t + 2 < NKS) WSPLIT(buf0, xa0, xa1, xa2, xa3);
        } else {
            CHUNK(buf1, 2 * t + 2, pH0, pM0, pH1, pM1);
            CHUNK(buf1, 2 * t + 3, qH0, qM0, qH1, qM1);
        }
    }

    #undef LOADX
    #undef WSPLIT
    #undef LOADB
    #undef CHUNK

    // ---- partial logits out (consumers only; deterministic) ----
    if (!producer) {
        const size_t pbase = ((size_t)sk * BB + row0) * 128;
        #pragma unroll
        for (int ms = 0; ms < 4; ++ms) {
            #pragma unroll
            for (int cb = 0; cb < 2; ++cb) {
                #pragma unroll
                for (int j = 0; j < 4; ++j) {
                    const int r = ms * 16 + kq * 4 + j;
                    const int c = (2 * cw + cb) * 16 + l15;
                    partial[pbase + (size_t)r * 128 + c] = acc[ms][cb][j];
                }
            }
        }
    }
}

// ------------------------------- epilogue ---------------------------------
template <int SK>
__global__ __launch_bounds__(512) void gating_epi(
    const float* __restrict__ partial,   // [SK][BB][128]
    const float* __restrict__ noise,     // [B, E]
    float* __restrict__ out)             // gates [B,E] then load [B,E]
{
    const int tid  = threadIdx.x;
    const int wv   = tid >> 6;
    const int lane = tid & 63;
    const int l15  = lane & 15;
    const int kq   = lane >> 4;
    const int grow = blockIdx.x * 32 + wv * 4 + kq;
    const int s    = l15;                // experts 4s..4s+3

    const float* pb = partial + (size_t)grow * 128 + 4 * s;
    float4 c4 = {0.f,0.f,0.f,0.f}, n4 = {0.f,0.f,0.f,0.f};
    #pragma unroll
    for (int k = 0; k < SK; ++k) {
        const float* p = pb + (size_t)k * BB * 128;
        float4 a = *reinterpret_cast<const float4*>(p);
        float4 b = *reinterpret_cast<const float4*>(p + 64);
        c4.x += a.x; c4.y += a.y; c4.z += a.z; c4.w += a.w;
        n4.x += b.x; n4.y += b.y; n4.z += b.z; n4.w += b.w;
    }

    float4 nz = *reinterpret_cast<const float4*>(noise + (size_t)grow * EE + 4 * s);

    float cc[4] = {c4.x, c4.y, c4.z, c4.w};
    float nl[4] = {n4.x, n4.y, n4.z, n4.w};
    float m1 = -3.4e38f, m2 = -3.4e38f;
    int   i1 = -1, i2 = -1;
    float cmax = -3.4e38f;
    #pragma unroll
    for (int j = 0; j < 4; ++j) {
        const int e = 4 * s + j;
        float sp  = fmaxf(nl[j], 0.0f) + log1pf(expf(-fabsf(nl[j])));  // softplus
        float nzj = (j == 0) ? nz.x : (j == 1) ? nz.y : (j == 2) ? nz.z : nz.w;
        float vno = fmaf(nzj * sp, NOISE_EPS, cc[j]);
        if (vno > m1)      { m2 = m1; i2 = i1; m1 = vno; i1 = e; }
        else if (vno > m2) { m2 = vno; i2 = e; }
        cmax = fmaxf(cmax, cc[j]);
    }

    // 16-lane reduce: top-2 with (value, lower-index) tiebreak + clean max
    #pragma unroll
    for (int m = 1; m < 16; m <<= 1) {
        float b1 = __shfl_xor(m1, m, 16);
        int  bi1 = __shfl_xor(i1, m, 16);
        float b2 = __shfl_xor(m2, m, 16);
        int  bi2 = __shfl_xor(i2, m, 16);
        cmax = fmaxf(cmax, __shfl_xor(cmax, m, 16));

        bool bwin = (b1 > m1) || (b1 == m1 && bi1 < i1);
        float t1; int ti1; float t2; int ti2;
        if (bwin) {
            t1 = b1; ti1 = bi1;
            bool aw = (m1 > b2) || (m1 == b2 && i1 < bi2);
            t2 = aw ? m1 : b2; ti2 = aw ? i1 : bi2;
        } else {
            t1 = m1; ti1 = i1;
            bool bw = (b1 > m2) || (b1 == m2 && bi1 < i2);
            t2 = bw ? b1 : m2; ti2 = bw ? bi1 : i2;
        }
        m1 = t1; i1 = ti1; m2 = t2; i2 = ti2;
    }

    float tq = expf(m2 - m1);
    float p1 = 1.0f / (1.0f + tq);
    float p2 = tq * p1;

    float e0 = expf(cc[0] - cmax);
    float e1 = expf(cc[1] - cmax);
    float e2 = expf(cc[2] - cmax);
    float e3 = expf(cc[3] - cmax);
    float sum = e0 + e1 + e2 + e3;
    #pragma unroll
    for (int m = 1; m < 16; m <<= 1) sum += __shfl_xor(sum, m, 16);
    float inv = 1.0f / sum;

    const int eb = 4 * s;
    float4 gt;
    gt.x = (eb     == i1) ? p1 : (eb     == i2) ? p2 : 0.0f;
    gt.y = (eb + 1 == i1) ? p1 : (eb + 1 == i2) ? p2 : 0.0f;
    gt.z = (eb + 2 == i1) ? p1 : (eb + 2 == i2) ? p2 : 0.0f;
    gt.w = (eb + 3 == i1) ? p1 : (eb + 3 == i2) ? p2 : 0.0f;
    float4 ld = {e0 * inv, e1 * inv, e2 * inv, e3 * inv};

    *reinterpret_cast<float4*>(out + (size_t)grow * EE + eb) = gt;
    *reinterpret_cast<float4*>(out + (size_t)BB * EE + (size_t)grow * EE + eb) = ld;
}

extern "C" void kernel_launch(void* const* d_in, const int* in_sizes, int n_in,
                              void* d_out, int out_size, void* d_ws, size_t ws_size,
                              hipStream_t stream) {
    const float* x     = (const float*)d_in[0];
    const float* gw    = (const float*)d_in[1];
    const float* ngw   = (const float*)d_in[2];
    const float* noise = (const float*)d_in[3];
    float* out = (float*)d_out;

    char*  wpk     = (char*)d_ws;                                // 2 MB packed w
    float* partial = (float*)(wpk + (size_t)2 * 1024 * 1024);    // SK * 4 MB

    const size_t MB = 1024 * 1024;

    hipLaunchKernelGGL(wsplit_pack, dim3(256), dim3(256), 0, stream, gw, ngw, wpk);

    if (ws_size >= 18 * MB) {
        hipLaunchKernelGGL(gating_main<4>, dim3((BB / BM) * 4), dim3(512), 0, stream,
                           x, wpk, partial);
        hipLaunchKernelGGL(gating_epi<4>, dim3(BB / 32), dim3(512), 0, stream,
                           partial, noise, out);
    } else if (ws_size >= 10 * MB) {
        hipLaunchKernelGGL(gating_main<2>, dim3((BB / BM) * 2), dim3(512), 0, stream,
                           x, wpk, partial);
        hipLaunchKernelGGL(gating_epi<2>, dim3(BB / 32), dim3(512), 0, stream,
                           partial, noise, out);
    } else {
        hipLaunchKernelGGL(gating_main<1>, dim3(BB / BM), dim3(512), 0, stream,
                           x, wpk, partial);
        hipLaunchKernelGGL(gating_epi<1>, dim3(BB / 32), dim3(512), 0, stream,
                           partial, noise, out);
    }
}